// Round 5
// baseline (230.114 us; speedup 1.0000x reference)
//
#include <hip/hip_runtime.h>
#include <hip/hip_fp16.h>

// InstantNGP hash-grid encoding, fp32 in/out.
// N_POINTS=1048576, N_LEVELS=16, F=2. SIZES[l]=2^(l+1), OFFS[l]=2^(l+1)-2.
// Hash: h = x*(P1*P2*P3) + y*(P2*P3) + z*P3 (mod 2^32).
//
// R8 (121us): wave-uniform levels (q,15-q) balanced, conflict-free transpose.
// Counters: VALU 25%, LDS-conflict 6%, HBM 15% -- no visible pipe dominant.
// Cycle audit attributes ~60-80% of iter time to the per-CU TA/L1 scattered-
// gather path (6144 lane-addresses/CU-iter for global levels 13..15 at
// ~2-2.5cyc/lane). R7's +33% regression when level 12 went global supports.
// R9: remove 1/3 of global lane-gathers: stage level 13 in LDS too
// (table 0..13 = 128KB fp16 + 16KB transpose = 144KB, 1 block/CU,
// 16 waves). Global = levels {14,15} on waves q=0,1 only, with loads issued
// early into regs and accumulated AFTER the partner LDS level (late vmcnt).

#define BLOCK 1024
#define NBLOCKS 512
#define ITERS 16            // 128 points per block-iter; 512*16*128 = 1048576
#define STAGED_ROWS 32766   // levels 0..13: sum 2^(l+1) = 2^15-2
#define TBL_LDS_BYTES 131072
#define LDS_BYTES (TBL_LDS_BYTES + 16 * 128 * 8)   // +16KB transpose = 147456

__device__ __forceinline__ float2 ldsRow(const unsigned* lds, unsigned idx) {
    unsigned u = lds[idx];
    __half2 h = *(__half2*)&u;
    return __half22float2(h);
}

// Corner hash sums (h000 + D[c]) and trilinear weights, inline (SROA-safe).
#define PREP(FRES, HARR, WARR) \
    unsigned HARR[8]; float WARR[8]; { \
        const float csx = (px + 1.0f) * (FRES); \
        const float csy = (py + 1.0f) * (FRES); \
        const float csz = (pz + 1.0f) * (FRES); \
        const float cfx = floorf(csx), cfy = floorf(csy), cfz = floorf(csz); \
        const float tx = csx - cfx, ty = csy - cfy, tz = csz - cfz; \
        const unsigned hh = (unsigned)cfx * HA + (unsigned)cfy * HB + (unsigned)cfz * HC; \
        const float ux = 1.0f - tx, uy = 1.0f - ty, uz = 1.0f - tz; \
        WARR[0] = ux*uy*uz; WARR[1] = tx*uy*uz; WARR[2] = ux*ty*uz; WARR[3] = tx*ty*uz; \
        WARR[4] = ux*uy*tz; WARR[5] = tx*uy*tz; WARR[6] = ux*ty*tz; WARR[7] = tx*ty*tz; \
        HARR[0] = hh;           HARR[1] = hh + HA;           \
        HARR[2] = hh + HB;      HARR[3] = hh + HA + HB;      \
        HARR[4] = hh + HC;      HARR[5] = hh + HA + HC;      \
        HARR[6] = hh + HB + HC; HARR[7] = hh + HA + HB + HC; \
    }

#define GATHER_LDS(HARR, WARR, MASK, OFF, O0, O1) \
    { _Pragma("unroll") for (int c = 0; c < 8; ++c) { \
        float2 f = ldsRow(lds_tb, (OFF) + ((HARR[c]) & (MASK))); \
        (O0) += f.x * WARR[c]; (O1) += f.y * WARR[c]; } }

__global__ __launch_bounds__(BLOCK) void ngp_encode_kernel(
    const float* __restrict__ coords,
    const float* __restrict__ table,
    float* __restrict__ out)
{
    extern __shared__ unsigned char lds_raw[];
    unsigned* lds_tb = (unsigned*)lds_raw;                   // 32766 half2 rows
    float2* lds_t = (float2*)(lds_raw + TBL_LDS_BYTES);      // [16][128], swizzled

    // ---- stage levels 0..13 as fp16 (float4 = 2 rows) ----
    {
        const float4* __restrict__ t4 = (const float4*)table;
        uint2* __restrict__ l2 = (uint2*)lds_tb;
        for (int r = threadIdx.x; r < STAGED_ROWS / 2; r += BLOCK) {  // 16383
            float4 v = t4[r];
            __half2 a = __floats2half2_rn(v.x, v.y);
            __half2 b = __floats2half2_rn(v.z, v.w);
            uint2 u;
            u.x = *(unsigned*)&a;
            u.y = *(unsigned*)&b;
            l2[r] = u;
        }
    }
    __syncthreads();

    constexpr unsigned P1 = 2654435761u, P2 = 29675113u, P3 = 123456789u;
    constexpr unsigned HA = P1 * P2 * P3;
    constexpr unsigned HB = P2 * P3;
    constexpr unsigned HC = P3;

    const float2* __restrict__ tb = (const float2*)table;
    float4* __restrict__ out4 = (float4*)out;

    // Wave-uniform level assignment: wave q owns levels (q, 15-q).
    // Global path only for lB in {14,15} (q<2); levels 0..13 from LDS.
    const int wv   = __builtin_amdgcn_readfirstlane((int)(threadIdx.x >> 6));
    const int q    = wv & 7;
    const int g    = wv >> 3;           // point-group 0/1
    const int lane = threadIdx.x & 63;
    const int pl   = g * 64 + lane;     // local point 0..127

    const int lA = q;
    const int lB = 15 - q;
    const unsigned maskA = (2u << lA) - 1u, offA = maskA - 1u;
    const unsigned maskB = (2u << lB) - 1u, offB = maskB - 1u;

    for (int it = 0; it < ITERS; ++it) {
        const int pbase = blockIdx.x * (ITERS * 128) + it * 128;
        const int p = pbase + pl;

        const float px = coords[3 * p + 0];
        const float py = coords[3 * p + 1];
        const float pz = coords[3 * p + 2];

        float oA0 = 0.0f, oA1 = 0.0f, oB0 = 0.0f, oB1 = 0.0f;

        if (q < 2) {
            // lB in {15,14}: global gathers issued into regs FIRST, then the
            // cheap LDS level runs, then the global accumulate (vmcnt wait
            // lands after ~300cy of useful work).
            PREP(512.0f, hB, wB)
            float2 gf0 = tb[offB + ((hB[0]) & maskB)];
            float2 gf1 = tb[offB + ((hB[1]) & maskB)];
            float2 gf2 = tb[offB + ((hB[2]) & maskB)];
            float2 gf3 = tb[offB + ((hB[3]) & maskB)];
            float2 gf4 = tb[offB + ((hB[4]) & maskB)];
            float2 gf5 = tb[offB + ((hB[5]) & maskB)];
            float2 gf6 = tb[offB + ((hB[6]) & maskB)];
            float2 gf7 = tb[offB + ((hB[7]) & maskB)];
            {
                const float fresA = (float)(16 << lA);
                PREP(fresA, hA, wA)
                GATHER_LDS(hA, wA, maskA, offA, oA0, oA1)
            }
            oB0 += gf0.x * wB[0]; oB1 += gf0.y * wB[0];
            oB0 += gf1.x * wB[1]; oB1 += gf1.y * wB[1];
            oB0 += gf2.x * wB[2]; oB1 += gf2.y * wB[2];
            oB0 += gf3.x * wB[3]; oB1 += gf3.y * wB[3];
            oB0 += gf4.x * wB[4]; oB1 += gf4.y * wB[4];
            oB0 += gf5.x * wB[5]; oB1 += gf5.y * wB[5];
            oB0 += gf6.x * wB[6]; oB1 += gf6.y * wB[6];
            oB0 += gf7.x * wB[7]; oB1 += gf7.y * wB[7];
        } else if (q < 5) {
            // lA in {2,3,4} (res<512) + lB in {13,12,11} LDS: two preps.
            {
                const float fresA = (float)(16 << lA);
                PREP(fresA, hA, wA)
                GATHER_LDS(hA, wA, maskA, offA, oA0, oA1)
            }
            {
                PREP(512.0f, hB, wB)
                GATHER_LDS(hB, wB, maskB, offB, oB0, oB1)
            }
        } else {
            // q=5,6,7: levels (5,10),(6,9),(7,8) -- all res 512, one prep.
            PREP(512.0f, hc, wc)
            GATHER_LDS(hc, wc, maskA, offA, oA0, oA1)
            GATHER_LDS(hc, wc, maskB, offB, oB0, oB1)
        }

        // ---- transpose through LDS: level-major [16][128] float2,
        // index XOR pl^(l&14) -> writes permuted-contiguous 512B/wave,
        // reads land 4 lanes per bank-pair (both bandwidth-optimal).
        lds_t[lA * 128 + (pl ^ (lA & 14))] = make_float2(oA0, oA1);
        lds_t[lB * 128 + (pl ^ (lB & 14))] = make_float2(oB0, oB1);
        __syncthreads();
        {
            const int j  = threadIdx.x;
            const int lp = j >> 3, qq = j & 7;
            float2 a = lds_t[(2 * qq + 0) * 128 + (lp ^ (2 * qq))];
            float2 b = lds_t[(2 * qq + 1) * 128 + (lp ^ (2 * qq))];
            out4[(size_t)pbase * 8 + j] = make_float4(a.x, a.y, b.x, b.y);
        }
        __syncthreads();
    }
}

extern "C" void kernel_launch(void* const* d_in, const int* in_sizes, int n_in,
                              void* d_out, int out_size, void* d_ws, size_t ws_size,
                              hipStream_t stream) {
    const float* coords = (const float*)d_in[0];
    const float* table  = (const float*)d_in[1];
    float* out = (float*)d_out;

    hipFuncSetAttribute((const void*)ngp_encode_kernel,
                        hipFuncAttributeMaxDynamicSharedMemorySize,
                        LDS_BYTES);

    ngp_encode_kernel<<<NBLOCKS, BLOCK, LDS_BYTES, stream>>>(coords, table, out);
}